// Round 1
// baseline (1317.343 us; speedup 1.0000x reference)
//
#include <hip/hip_runtime.h>
#include <hip/hip_bf16.h>
#include <cstdint>

#define D_MODEL 1024
#define D_STATE 16
#define BATCH   4096

using f32x4  = __attribute__((ext_vector_type(4))) float;
using bf16x8 = __attribute__((ext_vector_type(8))) short;

__device__ __forceinline__ unsigned short f2b(float f) {
  union { float f; unsigned int u; } v; v.f = f;
  unsigned int u = v.u;
  u = (u + 0x7fffu + ((u >> 16) & 1u)) >> 16;   // RTNE
  return (unsigned short)u;
}

__global__ void cvt_bf16(const float* __restrict__ src, unsigned short* __restrict__ dst, int n4) {
  int i = blockIdx.x * blockDim.x + threadIdx.x;
  if (i >= n4) return;
  float4 v = ((const float4*)src)[i];
  ushort4 o;
  o.x = f2b(v.x); o.y = f2b(v.y); o.z = f2b(v.z); o.w = f2b(v.w);
  ((ushort4*)dst)[i] = o;
}

__device__ __forceinline__ void async16(const unsigned short* g, unsigned short* l) {
  __builtin_amdgcn_global_load_lds((const __attribute__((address_space(1))) unsigned int*)g,
                                   (__attribute__((address_space(3))) unsigned int*)l,
                                   16, 0, 0);
}

// C = A(MxK) * W(NxK)^T, both bf16 K-major. 128x128 tile, BK=32, 4 waves in 2x2,
// each wave 64x64 via 4x4 frags of v_mfma_f32_16x16x32_bf16 (m97 structure).
__device__ __forceinline__ void gemm_mainloop(const unsigned short* __restrict__ A,
                                              const unsigned short* __restrict__ W,
                                              int K, int m0, int n0,
                                              f32x4 acc[4][4]) {
  __shared__ unsigned short As[128 * 32];
  __shared__ unsigned short Bs[128 * 32];
  const int tid  = threadIdx.x;
  const int lane = tid & 63;
  const int wv   = tid >> 6;
  const int wm   = wv >> 1;
  const int wn   = wv & 1;
  const int quad = lane >> 4;
  const int l16  = lane & 15;
#pragma unroll
  for (int i = 0; i < 4; ++i)
#pragma unroll
    for (int j = 0; j < 4; ++j) acc[i][j] = (f32x4){0.f, 0.f, 0.f, 0.f};
  int aoff[4], boff[4];
#pragma unroll
  for (int i = 0; i < 4; ++i) aoff[i] = (wm * 64 + i * 16 + l16) * 32 + quad * 8;
#pragma unroll
  for (int j = 0; j < 4; ++j) boff[j] = (wn * 64 + j * 16 + l16) * 32 + quad * 8;
  const int nkt = K >> 5;
  for (int kt = 0; kt < nkt; ++kt) {
    const int k0 = kt << 5;
    __syncthreads();   // previous iter's LDS reads done before overwrite
#pragma unroll
    for (int jj = 0; jj < 2; ++jj) {
      const int base = wv * 2048 + jj * 1024;     // byte offset in tile (wave-uniform)
      const int e    = (base >> 1) + lane * 8;    // this lane's element index
      const int r    = e >> 5, c = e & 31;
      async16(A + (size_t)(m0 + r) * K + k0 + c, (unsigned short*)((char*)As + base));
      async16(W + (size_t)(n0 + r) * K + k0 + c, (unsigned short*)((char*)Bs + base));
    }
    asm volatile("s_waitcnt vmcnt(0)" ::: "memory");
    __syncthreads();
    bf16x8 af[4], bfr[4];
#pragma unroll
    for (int i = 0; i < 4; ++i) af[i] = *(const bf16x8*)(As + aoff[i]);
#pragma unroll
    for (int j = 0; j < 4; ++j) bfr[j] = *(const bf16x8*)(Bs + boff[j]);
#pragma unroll
    for (int i = 0; i < 4; ++i)
#pragma unroll
      for (int j = 0; j < 4; ++j)
        acc[i][j] = __builtin_amdgcn_mfma_f32_16x16x32_bf16(af[i], bfr[j], acc[i][j], 0, 0, 0);
  }
}

// u = x@inw^T (tiles 0..7) ; delta = softplus(x@dtw^T + dtb) (tiles 8..15)
__global__ void gemm_ud(const unsigned short* __restrict__ xb,
                        const unsigned short* __restrict__ inwb,
                        const unsigned short* __restrict__ dtwb,
                        const float* __restrict__ dtb,
                        float* __restrict__ u, float* __restrict__ dl) {
  const int m0 = blockIdx.y * 128;
  const int nt = blockIdx.x;
  const bool isu = nt < 8;
  const int n0 = (isu ? nt : nt - 8) * 128;
  f32x4 acc[4][4];
  gemm_mainloop(xb, isu ? inwb : dtwb, D_MODEL, m0, n0, acc);
  const int tid = threadIdx.x, lane = tid & 63, wv = tid >> 6;
  const int wm = wv >> 1, wn = wv & 1, quad = lane >> 4, l16 = lane & 15;
#pragma unroll
  for (int i = 0; i < 4; ++i) {
#pragma unroll
    for (int j = 0; j < 4; ++j) {
      const int col = n0 + wn * 64 + j * 16 + l16;
#pragma unroll
      for (int reg = 0; reg < 4; ++reg) {
        const int row = m0 + wm * 64 + i * 16 + quad * 4 + reg;
        float v = acc[i][j][reg];
        if (isu) {
          u[(size_t)row * D_MODEL + col] = v;
        } else {
          v += dtb[col];
          float sp = (v > 15.f) ? v : log1pf(__expf(v));
          dl[(size_t)row * D_MODEL + col] = sp;
        }
      }
    }
  }
}

// bc = x@bcw^T fused with the whole SSM cell update.
// n = d*32 + which*16 + s : even 16-col frags are B_t, odd are C_t of the same d.
// Grid is (m-tiles, n-tiles) with m FASTEST: the 32 m-blocks sharing one 256 KB
// bcw n-tile launch back-to-back and are co-resident, so each bcw tile is
// HBM-fetched ~once instead of ~once per m-sweep (was 1.73 GB FETCH, ~5x ideal).
__global__ void gemm_bc(const unsigned short* __restrict__ xb,
                        const unsigned short* __restrict__ bcwb,
                        const float* __restrict__ h,
                        const float* __restrict__ Alog,
                        const float* __restrict__ Dp,
                        const float* __restrict__ u,
                        const float* __restrict__ dl,
                        float* __restrict__ hnew,
                        unsigned short* __restrict__ sy) {
  const int m0 = blockIdx.x * 128;   // fast dim: 32 m-tiles per n-tile group
  const int n0 = blockIdx.y * 128;   // slow dim: 256 n-tiles
  f32x4 acc[4][4];
  gemm_mainloop(xb, bcwb, D_MODEL, m0, n0, acc);
  const int tid = threadIdx.x, lane = tid & 63, wv = tid >> 6;
  const int wm = wv >> 1, wn = wv & 1, quad = lane >> 4, l16 = lane & 15;
#pragma unroll
  for (int p = 0; p < 2; ++p) {
    const int d = (n0 >> 5) + wn * 2 + p;
    const float Aneg = -__expf(Alog[d * D_STATE + l16]);
    const float Dd = Dp[d];
#pragma unroll
    for (int i = 0; i < 4; ++i) {
#pragma unroll
      for (int reg = 0; reg < 4; ++reg) {
        const int b = m0 + wm * 64 + i * 16 + quad * 4 + reg;
        const float db = dl[(size_t)b * D_MODEL + d];
        const float ub = u[(size_t)b * D_MODEL + d];
        const float hv = h[((size_t)b * D_MODEL + d) * D_STATE + l16];
        const float Bv = acc[i][2 * p][reg];
        const float Cv = acc[i][2 * p + 1][reg];
        const float dA = __expf(db * Aneg);
        const float hn = dA * hv + db * Bv * ub;
        hnew[((size_t)b * D_MODEL + d) * D_STATE + l16] = hn;
        float part = hn * Cv;
        part += __shfl_xor(part, 1, 16);
        part += __shfl_xor(part, 2, 16);
        part += __shfl_xor(part, 4, 16);
        part += __shfl_xor(part, 8, 16);
        if (l16 == 0) {
          const float y = part + Dd * ub;
          const float sil = y / (1.f + __expf(-y));
          sy[(size_t)b * D_MODEL + d] = f2b(sil);
        }
      }
    }
  }
}

__global__ void gemm_out(const unsigned short* __restrict__ syb,
                         const unsigned short* __restrict__ owb,
                         const float* __restrict__ ob,
                         float* __restrict__ out) {
  const int m0 = blockIdx.y * 128;
  const int n0 = blockIdx.x * 128;
  f32x4 acc[4][4];
  gemm_mainloop(syb, owb, D_MODEL, m0, n0, acc);
  const int tid = threadIdx.x, lane = tid & 63, wv = tid >> 6;
  const int wm = wv >> 1, wn = wv & 1, quad = lane >> 4, l16 = lane & 15;
#pragma unroll
  for (int i = 0; i < 4; ++i) {
#pragma unroll
    for (int j = 0; j < 4; ++j) {
      const int col = n0 + wn * 64 + j * 16 + l16;
      const float bias = ob[col];
#pragma unroll
      for (int reg = 0; reg < 4; ++reg) {
        const int row = m0 + wm * 64 + i * 16 + quad * 4 + reg;
        out[(size_t)row * D_MODEL + col] = acc[i][j][reg] + bias;
      }
    }
  }
}

extern "C" void kernel_launch(void* const* d_in, const int* in_sizes, int n_in,
                              void* d_out, int out_size, void* d_ws, size_t ws_size,
                              hipStream_t stream) {
  const float* x    = (const float*)d_in[0];
  const float* h    = (const float*)d_in[1];
  const float* inw  = (const float*)d_in[2];
  const float* dtw  = (const float*)d_in[3];
  const float* dtb  = (const float*)d_in[4];
  const float* bcw  = (const float*)d_in[5];
  const float* Alog = (const float*)d_in[6];
  const float* Dp   = (const float*)d_in[7];
  const float* ow   = (const float*)d_in[8];
  const float* ob   = (const float*)d_in[9];

  float* out  = (float*)d_out;
  float* hnew = out + (size_t)BATCH * D_MODEL;

  char* ws = (char*)d_ws;
  unsigned short* xb   = (unsigned short*)(ws);                        // 8 MB
  unsigned short* inwb = (unsigned short*)(ws + (size_t)(8u  << 20));  // 2 MB
  unsigned short* dtwb = (unsigned short*)(ws + (size_t)(10u << 20));  // 2 MB
  unsigned short* bcwb = (unsigned short*)(ws + (size_t)(12u << 20));  // 64 MB
  unsigned short* owb  = (unsigned short*)(ws + (size_t)(76u << 20));  // 2 MB
  float*          u    = (float*)(ws + (size_t)(78u << 20));           // 16 MB
  float*          dl   = (float*)(ws + (size_t)(94u << 20));           // 16 MB
  unsigned short* sy   = (unsigned short*)(ws + (size_t)(110u << 20)); // 8 MB

  {
    int n4 = (BATCH * D_MODEL) >> 2;
    cvt_bf16<<<(n4 + 255) / 256, 256, 0, stream>>>(x, xb, n4);
    n4 = (D_MODEL * D_MODEL) >> 2;
    cvt_bf16<<<(n4 + 255) / 256, 256, 0, stream>>>(inw, inwb, n4);
    cvt_bf16<<<(n4 + 255) / 256, 256, 0, stream>>>(dtw, dtwb, n4);
    cvt_bf16<<<(n4 + 255) / 256, 256, 0, stream>>>(ow, owb, n4);
    n4 = (D_MODEL * D_STATE * 2 * D_MODEL) >> 2;
    cvt_bf16<<<(n4 + 255) / 256, 256, 0, stream>>>(bcw, bcwb, n4);
  }

  gemm_ud<<<dim3(16, 32), 256, 0, stream>>>(xb, inwb, dtwb, dtb, u, dl);
  gemm_bc<<<dim3(32, 256), 256, 0, stream>>>(xb, bcwb, h, Alog, Dp, u, dl, hnew, sy);
  gemm_out<<<dim3(8, 32), 256, 0, stream>>>(sy, owb, ob, out);
}

// Round 3
// 1048.733 us; speedup vs baseline: 1.2561x; 1.2561x over previous
//
#include <hip/hip_runtime.h>
#include <hip/hip_bf16.h>
#include <cstdint>

#define D_MODEL 1024
#define D_STATE 16
#define BATCH   4096

using f32x4  = __attribute__((ext_vector_type(4))) float;
using bf16x8 = __attribute__((ext_vector_type(8))) short;

__device__ __forceinline__ unsigned short f2b(float f) {
  union { float f; unsigned int u; } v; v.f = f;
  unsigned int u = v.u;
  u = (u + 0x7fffu + ((u >> 16) & 1u)) >> 16;   // RTNE
  return (unsigned short)u;
}

// One fused conversion kernel: x | in_proj_w | dt_proj_w | out_proj_w | bc_proj_w
__global__ void cvt_all(const float* __restrict__ x,  const float* __restrict__ inw,
                        const float* __restrict__ dtw, const float* __restrict__ ow,
                        const float* __restrict__ bcw,
                        unsigned short* __restrict__ xb,  unsigned short* __restrict__ inwb,
                        unsigned short* __restrict__ dtwb, unsigned short* __restrict__ owb,
                        unsigned short* __restrict__ bcwb) {
  const int N_X = (BATCH * D_MODEL) >> 2;
  const int N_W = (D_MODEL * D_MODEL) >> 2;
  const int N_B = (D_MODEL * D_STATE * 2 * D_MODEL) >> 2;
  int i = blockIdx.x * blockDim.x + threadIdx.x;
  const float* src; unsigned short* dst; int off;
  if      (i < N_X)             { src = x;   dst = xb;   off = i; }
  else if (i < N_X + N_W)       { src = inw; dst = inwb; off = i - N_X; }
  else if (i < N_X + 2 * N_W)   { src = dtw; dst = dtwb; off = i - N_X - N_W; }
  else if (i < N_X + 3 * N_W)   { src = ow;  dst = owb;  off = i - N_X - 2 * N_W; }
  else if (i < N_X + 3*N_W + N_B){ src = bcw; dst = bcwb; off = i - N_X - 3 * N_W; }
  else return;
  float4 v = ((const float4*)src)[off];
  ushort4 o;
  o.x = f2b(v.x); o.y = f2b(v.y); o.z = f2b(v.z); o.w = f2b(v.w);
  ((ushort4*)dst)[off] = o;
}

__device__ __forceinline__ void async16(const unsigned short* g, unsigned short* l) {
  __builtin_amdgcn_global_load_lds((const __attribute__((address_space(1))) unsigned int*)g,
                                   (__attribute__((address_space(3))) unsigned int*)l,
                                   16, 0, 0);
}

// C = A(MxK) * W(NxK)^T, both bf16 K-major. 128x128 tile, BK=32, 4 waves in 2x2,
// each wave 64x64 via 4x4 frags of v_mfma_f32_16x16x32_bf16.
// 2-phase double-buffered pipeline (T3-minimum): stage tile kt+1 BEFORE computing
// tile kt; single __syncthreads() per K-step (its built-in vmcnt/lgkmcnt drain is
// the only wait). Next-tile HBM/L2 latency hides under ds_read+MFMA of current.
__device__ __forceinline__ void gemm_mainloop(const unsigned short* __restrict__ A,
                                              const unsigned short* __restrict__ W,
                                              int K, int m0, int n0,
                                              f32x4 acc[4][4]) {
  __shared__ unsigned short As[2][128 * 32];
  __shared__ unsigned short Bs[2][128 * 32];
  const int tid  = threadIdx.x;
  const int lane = tid & 63;
  const int wv   = tid >> 6;
  const int wm   = wv >> 1;
  const int wn   = wv & 1;
  const int quad = lane >> 4;
  const int l16  = lane & 15;
#pragma unroll
  for (int i = 0; i < 4; ++i)
#pragma unroll
    for (int j = 0; j < 4; ++j) acc[i][j] = (f32x4){0.f, 0.f, 0.f, 0.f};
  int aoff[4], boff[4];
#pragma unroll
  for (int i = 0; i < 4; ++i) aoff[i] = (wm * 64 + i * 16 + l16) * 32 + quad * 8;
#pragma unroll
  for (int j = 0; j < 4; ++j) boff[j] = (wn * 64 + j * 16 + l16) * 32 + quad * 8;

  // Per-lane staging geometry: LDS dest is wave-uniform base + lane*16B;
  // global source pre-matched to that order (linear [row][32] tile layout).
  const int base0 = wv * 2048;            // bytes within tile, jj=0
  const int base1 = base0 + 1024;         // jj=1
  const int e0 = (base0 >> 1) + lane * 8, r0 = e0 >> 5, c0 = e0 & 31;
  const int e1 = (base1 >> 1) + lane * 8, r1 = e1 >> 5, c1 = e1 & 31;
  const unsigned short* Ap0 = A + (size_t)(m0 + r0) * K + c0;
  const unsigned short* Ap1 = A + (size_t)(m0 + r1) * K + c1;
  const unsigned short* Wp0 = W + (size_t)(n0 + r0) * K + c0;
  const unsigned short* Wp1 = W + (size_t)(n0 + r1) * K + c1;

#define STAGE(buf, k0s) do {                                        \
    char* a_ = (char*)As[(buf)]; char* b_ = (char*)Bs[(buf)];       \
    async16(Ap0 + (k0s), (unsigned short*)(a_ + base0));            \
    async16(Wp0 + (k0s), (unsigned short*)(b_ + base0));            \
    async16(Ap1 + (k0s), (unsigned short*)(a_ + base1));            \
    async16(Wp1 + (k0s), (unsigned short*)(b_ + base1));            \
  } while (0)

#define KSTEP(buf, kt) do {                                                      \
    if ((kt) + 1 < nkt) STAGE(1 - (buf), ((kt) + 1) << 5);                       \
    const unsigned short* as_ = As[(buf)];                                       \
    const unsigned short* bs_ = Bs[(buf)];                                       \
    bf16x8 af[4], bfr[4];                                                        \
    _Pragma("unroll") for (int i_ = 0; i_ < 4; ++i_)                             \
      af[i_] = *(const bf16x8*)(as_ + aoff[i_]);                                 \
    _Pragma("unroll") for (int j_ = 0; j_ < 4; ++j_)                             \
      bfr[j_] = *(const bf16x8*)(bs_ + boff[j_]);                                \
    _Pragma("unroll") for (int i_ = 0; i_ < 4; ++i_)                             \
      _Pragma("unroll") for (int j_ = 0; j_ < 4; ++j_)                           \
        acc[i_][j_] = __builtin_amdgcn_mfma_f32_16x16x32_bf16(af[i_], bfr[j_],   \
                                                              acc[i_][j_], 0,0,0);\
    __syncthreads();                                                             \
  } while (0)

  const int nkt = K >> 5;          // always even here (K = 1024)
  STAGE(0, 0);
  __syncthreads();                 // drains prologue staging (vmcnt inside)
  for (int kt = 0; kt < nkt; kt += 2) {
    KSTEP(0, kt);
    KSTEP(1, kt + 1);
  }
#undef STAGE
#undef KSTEP
}

// u = x@inw^T (tiles 0..7) ; delta = softplus(x@dtw^T + dtb) (tiles 8..15)
__global__ void gemm_ud(const unsigned short* __restrict__ xb,
                        const unsigned short* __restrict__ inwb,
                        const unsigned short* __restrict__ dtwb,
                        const float* __restrict__ dtb,
                        float* __restrict__ u, float* __restrict__ dl) {
  const int m0 = blockIdx.y * 128;
  const int nt = blockIdx.x;
  const bool isu = nt < 8;
  const int n0 = (isu ? nt : nt - 8) * 128;
  f32x4 acc[4][4];
  gemm_mainloop(xb, isu ? inwb : dtwb, D_MODEL, m0, n0, acc);
  const int tid = threadIdx.x, lane = tid & 63, wv = tid >> 6;
  const int wm = wv >> 1, wn = wv & 1, quad = lane >> 4, l16 = lane & 15;
#pragma unroll
  for (int i = 0; i < 4; ++i) {
#pragma unroll
    for (int j = 0; j < 4; ++j) {
      const int col = n0 + wn * 64 + j * 16 + l16;
#pragma unroll
      for (int reg = 0; reg < 4; ++reg) {
        const int row = m0 + wm * 64 + i * 16 + quad * 4 + reg;
        float v = acc[i][j][reg];
        if (isu) {
          u[(size_t)row * D_MODEL + col] = v;
        } else {
          v += dtb[col];
          float sp = (v > 15.f) ? v : log1pf(__expf(v));
          dl[(size_t)row * D_MODEL + col] = sp;
        }
      }
    }
  }
}

// bc = x@bcw^T fused with the whole SSM cell update.
// n = d*32 + which*16 + s : even 16-col frags are B_t, odd are C_t of the same d.
// Grid is (m-tiles, n-tiles) with m FASTEST for bcw L2/L3 reuse.
__global__ void gemm_bc(const unsigned short* __restrict__ xb,
                        const unsigned short* __restrict__ bcwb,
                        const float* __restrict__ h,
                        const float* __restrict__ Alog,
                        const float* __restrict__ Dp,
                        const float* __restrict__ u,
                        const float* __restrict__ dl,
                        float* __restrict__ hnew,
                        unsigned short* __restrict__ sy) {
  const int m0 = blockIdx.x * 128;   // fast dim: 32 m-tiles per n-tile group
  const int n0 = blockIdx.y * 128;   // slow dim: 256 n-tiles
  f32x4 acc[4][4];
  gemm_mainloop(xb, bcwb, D_MODEL, m0, n0, acc);
  const int tid = threadIdx.x, lane = tid & 63, wv = tid >> 6;
  const int wm = wv >> 1, wn = wv & 1, quad = lane >> 4, l16 = lane & 15;

  const int dbase = (n0 >> 5) + wn * 2;           // even; this wave owns d = dbase, dbase+1
  const float Aneg0 = -__expf(Alog[(dbase + 0) * D_STATE + l16]);
  const float Aneg1 = -__expf(Alog[(dbase + 1) * D_STATE + l16]);
  const float Dd0 = Dp[dbase + 0];
  const float Dd1 = Dp[dbase + 1];
#pragma unroll
  for (int i = 0; i < 4; ++i) {
#pragma unroll
    for (int reg = 0; reg < 4; ++reg) {
      const int b = m0 + wm * 64 + i * 16 + quad * 4 + reg;
      const float2 db2 = *(const float2*)(dl + (size_t)b * D_MODEL + dbase);
      const float2 ub2 = *(const float2*)(u  + (size_t)b * D_MODEL + dbase);
      // p = 0 : acc[i][0]=B, acc[i][1]=C for d = dbase
      const float hv0 = h[((size_t)b * D_MODEL + dbase + 0) * D_STATE + l16];
      const float dA0 = __expf(db2.x * Aneg0);
      const float hn0 = dA0 * hv0 + db2.x * acc[i][0][reg] * ub2.x;
      hnew[((size_t)b * D_MODEL + dbase + 0) * D_STATE + l16] = hn0;
      float part0 = hn0 * acc[i][1][reg];
      part0 += __shfl_xor(part0, 1, 16);
      part0 += __shfl_xor(part0, 2, 16);
      part0 += __shfl_xor(part0, 4, 16);
      part0 += __shfl_xor(part0, 8, 16);
      // p = 1 : acc[i][2]=B, acc[i][3]=C for d = dbase+1
      const float hv1 = h[((size_t)b * D_MODEL + dbase + 1) * D_STATE + l16];
      const float dA1 = __expf(db2.y * Aneg1);
      const float hn1 = dA1 * hv1 + db2.y * acc[i][2][reg] * ub2.y;
      hnew[((size_t)b * D_MODEL + dbase + 1) * D_STATE + l16] = hn1;
      float part1 = hn1 * acc[i][3][reg];
      part1 += __shfl_xor(part1, 1, 16);
      part1 += __shfl_xor(part1, 2, 16);
      part1 += __shfl_xor(part1, 4, 16);
      part1 += __shfl_xor(part1, 8, 16);
      if (l16 == 0) {
        const float y0 = part0 + Dd0 * ub2.x;
        const float y1 = part1 + Dd1 * ub2.y;
        const float s0 = y0 / (1.f + __expf(-y0));
        const float s1 = y1 / (1.f + __expf(-y1));
        *(unsigned int*)(sy + (size_t)b * D_MODEL + dbase) =
            (unsigned int)f2b(s0) | ((unsigned int)f2b(s1) << 16);
      }
    }
  }
}

__global__ void gemm_out(const unsigned short* __restrict__ syb,
                         const unsigned short* __restrict__ owb,
                         const float* __restrict__ ob,
                         float* __restrict__ out) {
  const int m0 = blockIdx.y * 128;
  const int n0 = blockIdx.x * 128;
  f32x4 acc[4][4];
  gemm_mainloop(syb, owb, D_MODEL, m0, n0, acc);
  const int tid = threadIdx.x, lane = tid & 63, wv = tid >> 6;
  const int wm = wv >> 1, wn = wv & 1, quad = lane >> 4, l16 = lane & 15;
#pragma unroll
  for (int i = 0; i < 4; ++i) {
#pragma unroll
    for (int j = 0; j < 4; ++j) {
      const int col = n0 + wn * 64 + j * 16 + l16;
      const float bias = ob[col];
#pragma unroll
      for (int reg = 0; reg < 4; ++reg) {
        const int row = m0 + wm * 64 + i * 16 + quad * 4 + reg;
        out[(size_t)row * D_MODEL + col] = acc[i][j][reg] + bias;
      }
    }
  }
}

extern "C" void kernel_launch(void* const* d_in, const int* in_sizes, int n_in,
                              void* d_out, int out_size, void* d_ws, size_t ws_size,
                              hipStream_t stream) {
  const float* x    = (const float*)d_in[0];
  const float* h    = (const float*)d_in[1];
  const float* inw  = (const float*)d_in[2];
  const float* dtw  = (const float*)d_in[3];
  const float* dtb  = (const float*)d_in[4];
  const float* bcw  = (const float*)d_in[5];
  const float* Alog = (const float*)d_in[6];
  const float* Dp   = (const float*)d_in[7];
  const float* ow   = (const float*)d_in[8];
  const float* ob   = (const float*)d_in[9];

  float* out  = (float*)d_out;
  float* hnew = out + (size_t)BATCH * D_MODEL;

  char* ws = (char*)d_ws;
  unsigned short* xb   = (unsigned short*)(ws);                        // 8 MB
  unsigned short* inwb = (unsigned short*)(ws + (size_t)(8u  << 20));  // 2 MB
  unsigned short* dtwb = (unsigned short*)(ws + (size_t)(10u << 20));  // 2 MB
  unsigned short* bcwb = (unsigned short*)(ws + (size_t)(12u << 20));  // 64 MB
  unsigned short* owb  = (unsigned short*)(ws + (size_t)(76u << 20));  // 2 MB
  float*          u    = (float*)(ws + (size_t)(78u << 20));           // 16 MB
  float*          dl   = (float*)(ws + (size_t)(94u << 20));           // 16 MB
  unsigned short* sy   = (unsigned short*)(ws + (size_t)(110u << 20)); // 8 MB

  {
    const int N_X = (BATCH * D_MODEL) >> 2;
    const int N_W = (D_MODEL * D_MODEL) >> 2;
    const int N_B = (D_MODEL * D_STATE * 2 * D_MODEL) >> 2;
    const int total = N_X + 3 * N_W + N_B;
    cvt_all<<<(total + 255) / 256, 256, 0, stream>>>(x, inw, dtw, ow, bcw,
                                                     xb, inwb, dtwb, owb, bcwb);
  }

  gemm_ud<<<dim3(16, 32), 256, 0, stream>>>(xb, inwb, dtwb, dtb, u, dl);
  gemm_bc<<<dim3(32, 256), 256, 0, stream>>>(xb, bcwb, h, Alog, Dp, u, dl, hnew, sy);
  gemm_out<<<dim3(8, 32), 256, 0, stream>>>(sy, owb, ob, out);
}